// Round 1
// baseline (208.335 us; speedup 1.0000x reference)
//
#include <hip/hip_runtime.h>

// Problem constants (traced from the Python reference's stride schedule):
//   x: (32, 512, 512, 32) fp32;  out: (32, 284, 205, 32) fp32
//   out[b,r,c,z] = sum_{di,dj} K[di][dj] * x[b, ROW(r)+di, COL(c)+dj, z]
//   K = [1 2 1; 2 4 2; 1 2 1]  (separable [1,2,1] x [1,2,1])
// Closed-form sampled indices (verified against the while-loop schedule):
//   ROW(r) = r<58 ? 3r : (r<228 ? r+114 : 3r-340)      // 0..509
//   COL(c) = c<129 ? c : 5c-512                         // 0..508

#define B_   32
#define NX_  512
#define NY_  512
#define NZ_  32
#define NR_  284
#define NC_  205
#define ZQ_  (NZ_/4)   // 8 float4 per (b,x,y)

__device__ __forceinline__ int row_of(int r) {
    return (r < 58) ? 3 * r : ((r < 228) ? r + 114 : 3 * r - 340);
}
__device__ __forceinline__ int col_of(int c) {
    return (c < 129) ? c : 5 * c - 512;
}

__global__ __launch_bounds__(256)
void blur_sample_kernel(const float* __restrict__ x, float* __restrict__ out) {
    const int zq = threadIdx.x & 7;        // z-quad 0..7 (contiguous 128B per column)
    const int cl = threadIdx.x >> 3;       // 0..31 columns per block
    const int c  = blockIdx.x * 32 + cl;
    const int r  = blockIdx.y;
    const int b  = blockIdx.z;
    if (c >= NC_) return;

    const int row0 = row_of(r);
    const int col0 = col_of(c);

    const float4* xp = reinterpret_cast<const float4*>(x)
                     + ((size_t)(b * NX_ + row0) * NY_ + col0) * ZQ_ + zq;

    float4 acc = make_float4(0.f, 0.f, 0.f, 0.f);
    #pragma unroll
    for (int di = 0; di < 3; ++di) {
        const float4* p = xp + (size_t)di * (NY_ * ZQ_);
        const float4 a  = p[0];          // col+0
        const float4 bb = p[ZQ_];        // col+1
        const float4 cc = p[2 * ZQ_];    // col+2
        const float w = (di == 1) ? 2.0f : 1.0f;
        acc.x += w * (a.x + 2.0f * bb.x + cc.x);
        acc.y += w * (a.y + 2.0f * bb.y + cc.y);
        acc.z += w * (a.z + 2.0f * bb.z + cc.z);
        acc.w += w * (a.w + 2.0f * bb.w + cc.w);
    }

    float4* op = reinterpret_cast<float4*>(out)
               + ((size_t)(b * NR_ + r) * NC_ + c) * ZQ_ + zq;
    *op = acc;
}

extern "C" void kernel_launch(void* const* d_in, const int* in_sizes, int n_in,
                              void* d_out, int out_size, void* d_ws, size_t ws_size,
                              hipStream_t stream) {
    const float* x = (const float*)d_in[0];
    float* out = (float*)d_out;
    dim3 block(256);
    dim3 grid((NC_ + 31) / 32, NR_, B_);   // 7 x 284 x 32 blocks
    blur_sample_kernel<<<grid, block, 0, stream>>>(x, out);
}

// Round 2
// 205.520 us; speedup vs baseline: 1.0137x; 1.0137x over previous
//
#include <hip/hip_runtime.h>

// out[b,r,c,z] = sum_{di,dj} K[di][dj] * x[b, ROW(r)+di, COL(c)+dj, z]
//   x: (32, 512, 512, 32) fp32;  out: (32, 284, 205, 32) fp32
//   K = [1 2 1; 2 4 2; 1 2 1]  (separable [1,2,1] x [1,2,1])
//   ROW(r) = r<58 ? 3r : (r<228 ? r+114 : 3r-340)   // stride 3 / 1 / 3
//   COL(c) = c<129 ? c : 5c-512                      // stride 1 / 5
// Middle-row region (60% of rows) strides by 1 -> consecutive output rows
// share 2/3 input rows. Process R=8 output rows per block with a rolling
// window of horizontal sums to internalize that reuse in registers.

#define B_   32
#define NX_  512
#define NY_  512
#define NZ_  32
#define NR_  284
#define NC_  205
#define ZQ_  (NZ_/4)   // 8 float4 per (b,x,y)
#define R_   8         // output rows per block

__device__ __forceinline__ int row_of(int r) {
    return (r < 58) ? 3 * r : ((r < 228) ? r + 114 : 3 * r - 340);
}
__device__ __forceinline__ int col_of(int c) {
    return (c < 129) ? c : 5 * c - 512;
}

__global__ __launch_bounds__(256)
void blur_roll_kernel(const float* __restrict__ x, float* __restrict__ out) {
    const int zq = threadIdx.x & 7;        // z-quad 0..7 (128B contiguous per col)
    const int cl = threadIdx.x >> 3;       // 0..31 cols per block
    const int c  = blockIdx.x * 32 + cl;
    const int r0 = blockIdx.y * R_;
    const int b  = blockIdx.z;
    if (c >= NC_) return;

    const int col0 = col_of(c);
    const float4* xb = reinterpret_cast<const float4*>(x)
                     + (size_t)b * (NX_ * NY_ * ZQ_) + zq;
    float4* ob = reinterpret_cast<float4*>(out)
               + ((size_t)b * NR_ * NC_) * ZQ_ + (size_t)c * ZQ_ + zq;

    // horizontal [1,2,1] sum for one input row
    auto hsum = [&](int row) -> float4 {
        const float4* p = xb + ((size_t)row * NY_ + col0) * ZQ_;
        const float4 a  = p[0];
        const float4 bb = p[ZQ_];
        const float4 cc = p[2 * ZQ_];
        float4 h;
        h.x = (a.x + cc.x) + 2.0f * bb.x;
        h.y = (a.y + cc.y) + 2.0f * bb.y;
        h.z = (a.z + cc.z) + 2.0f * bb.z;
        h.w = (a.w + cc.w) + 2.0f * bb.w;
        return h;
    };
    auto vsum = [](const float4& h0, const float4& h1, const float4& h2) -> float4 {
        float4 v;
        v.x = (h0.x + h2.x) + 2.0f * h1.x;
        v.y = (h0.y + h2.y) + 2.0f * h1.y;
        v.z = (h0.z + h2.z) + 2.0f * h1.z;
        v.w = (h0.w + h2.w) + 2.0f * h1.w;
        return v;
    };

    const int rEnd = (r0 + R_ < NR_) ? r0 + R_ : NR_;

    int row = row_of(r0);
    float4 h0 = hsum(row);
    float4 h1 = hsum(row + 1);
    float4 h2 = hsum(row + 2);
    ob[(size_t)r0 * NC_ * ZQ_] = vsum(h0, h1, h2);

    for (int rr = r0 + 1; rr < rEnd; ++rr) {
        const int nrow = row_of(rr);
        if (nrow == row + 1) {           // stride-1 region: slide window
            h0 = h1; h1 = h2;
            h2 = hsum(nrow + 2);
        } else {                          // stride-3 region: reload
            h0 = hsum(nrow);
            h1 = hsum(nrow + 1);
            h2 = hsum(nrow + 2);
        }
        row = nrow;
        ob[(size_t)rr * NC_ * ZQ_] = vsum(h0, h1, h2);
    }
}

extern "C" void kernel_launch(void* const* d_in, const int* in_sizes, int n_in,
                              void* d_out, int out_size, void* d_ws, size_t ws_size,
                              hipStream_t stream) {
    const float* x = (const float*)d_in[0];
    float* out = (float*)d_out;
    dim3 block(256);
    dim3 grid((NC_ + 31) / 32, (NR_ + R_ - 1) / R_, B_);   // 7 x 36 x 32
    blur_roll_kernel<<<grid, block, 0, stream>>>(x, out);
}

// Round 4
// 198.941 us; speedup vs baseline: 1.0472x; 1.0331x over previous
//
#include <hip/hip_runtime.h>

// out[b,r,c,z] = sum_{di,dj} K[di][dj] * x[b, ROW(r)+di, COL(c)+dj, z]
//   x: (32, 512, 512, 32) fp32;  out: (32, 284, 205, 32) fp32
//   K = [1 2 1; 2 4 2; 1 2 1]  (separable [1,2,1] x [1,2,1])
//   ROW(r) = r<58 ? 3r : (r<228 ? r+114 : 3r-340)   // stride 3 / 1 / 3
//   COL(c) = c<129 ? c : 5c-512                      // stride 1 / 5
// R=8 rows/block with rolling horizontal-sum window (internalizes stride-1
// row reuse). Output stores are NON-TEMPORAL (nt flag): the 238 MB write
// stream is never re-read; keep it out of L2/L3 to preserve input-row reuse.
// NOTE: __builtin_nontemporal_store needs a NATIVE vector type, not HIP's
// float4 class -> use ext_vector_type(4).

#define B_   32
#define NX_  512
#define NY_  512
#define NZ_  32
#define NR_  284
#define NC_  205
#define ZQ_  (NZ_/4)   // 8 fx4 per (b,x,y)
#define R_   8         // output rows per block

typedef float fx4 __attribute__((ext_vector_type(4)));

__device__ __forceinline__ int row_of(int r) {
    return (r < 58) ? 3 * r : ((r < 228) ? r + 114 : 3 * r - 340);
}
__device__ __forceinline__ int col_of(int c) {
    return (c < 129) ? c : 5 * c - 512;
}

__global__ __launch_bounds__(256)
void blur_roll_nt_kernel(const float* __restrict__ x, float* __restrict__ out) {
    const int zq = threadIdx.x & 7;        // z-quad 0..7 (128B contiguous per col)
    const int cl = threadIdx.x >> 3;       // 0..31 cols per block
    const int c  = blockIdx.x * 32 + cl;
    const int r0 = blockIdx.y * R_;
    const int b  = blockIdx.z;
    if (c >= NC_) return;

    const int col0 = col_of(c);
    const fx4* xb = reinterpret_cast<const fx4*>(x)
                  + (size_t)b * (NX_ * NY_ * ZQ_) + zq;
    fx4* ob = reinterpret_cast<fx4*>(out)
            + ((size_t)b * NR_ * NC_) * ZQ_ + (size_t)c * ZQ_ + zq;

    auto hsum = [&](int row) -> fx4 {
        const fx4* p = xb + ((size_t)row * NY_ + col0) * ZQ_;
        const fx4 a  = p[0];
        const fx4 bb = p[ZQ_];
        const fx4 cc = p[2 * ZQ_];
        return (a + cc) + 2.0f * bb;
    };
    auto vstore = [](fx4* p, const fx4& h0, const fx4& h1, const fx4& h2) {
        const fx4 v = (h0 + h2) + 2.0f * h1;
        __builtin_nontemporal_store(v, p);   // bypass L2/L3 allocation
    };

    const int rEnd = (r0 + R_ < NR_) ? r0 + R_ : NR_;

    int row = row_of(r0);
    fx4 h0 = hsum(row);
    fx4 h1 = hsum(row + 1);
    fx4 h2 = hsum(row + 2);
    vstore(&ob[(size_t)r0 * NC_ * ZQ_], h0, h1, h2);

    for (int rr = r0 + 1; rr < rEnd; ++rr) {
        const int nrow = row_of(rr);
        if (nrow == row + 1) {           // stride-1 region: slide window
            h0 = h1; h1 = h2;
            h2 = hsum(nrow + 2);
        } else {                          // stride-3 region: reload
            h0 = hsum(nrow);
            h1 = hsum(nrow + 1);
            h2 = hsum(nrow + 2);
        }
        row = nrow;
        vstore(&ob[(size_t)rr * NC_ * ZQ_], h0, h1, h2);
    }
}

extern "C" void kernel_launch(void* const* d_in, const int* in_sizes, int n_in,
                              void* d_out, int out_size, void* d_ws, size_t ws_size,
                              hipStream_t stream) {
    const float* x = (const float*)d_in[0];
    float* out = (float*)d_out;
    dim3 block(256);
    dim3 grid((NC_ + 31) / 32, (NR_ + R_ - 1) / R_, B_);   // 7 x 36 x 32
    blur_roll_nt_kernel<<<grid, block, 0, stream>>>(x, out);
}